// Round 10
// baseline (114166.785 us; speedup 1.0000x reference)
//
#include <hip/hip_runtime.h>
#include <math.h>

#define NB 256
#define NN 256
#define NK 128
#define ND 256
#define NH 512
#define NT 1024

// output layout (floats): x | f_out | u | p_u
#define OUT_X 0
#define OUT_F 65536
#define OUT_U 131072
#define OUT_P 196608

// per-batch ws float offsets
#define EPB   65280            // E levels 1..8 (255*256)
#define SP6O  EPB              // bn6 spec: 4*256
#define S1O   (SP6O + 1024)    // 2*256
#define S2O   (S1O + 512)      // 4*256
#define S3O   (S2O + 1024)     // 8*256
#define LOFFI (S3O + 2048)     // 256 ints (decision-bit slabs)
#define BPB   (LOFFI + 256)

__host__ __device__ __forceinline__ int loff(int d) { return 256 - (1 << (9 - d)); }

// ---- 8-row weight-register load (ping-pong half) ----
#define LD8(W, KOFF, LDWROW)                                              \
  {                                                                       \
    _Pragma("unroll") for (int j = 0; j < 8; ++j) W[j] =                  \
        *(const float2*)(Wp + (size_t)((KOFF) + j) * (LDWROW));           \
  }

#define G_HALF(W, OFF, RR, SRCBASE)                                       \
  {                                                                       \
    _Pragma("unroll") for (int r = 0; r < RR; ++r) {                      \
      const float4 x0 = *(const float4*)(SRCBASE + r * 512 + (OFF));      \
      const float4 x1 = *(const float4*)(SRCBASE + r * 512 + (OFF) + 4);  \
      a0[r] += x0.x * W[0].x + x0.y * W[1].x + x0.z * W[2].x +            \
               x0.w * W[3].x + x1.x * W[4].x + x1.y * W[5].x +            \
               x1.z * W[6].x + x1.w * W[7].x;                             \
      a1[r] += x0.x * W[0].y + x0.y * W[1].y + x0.z * W[2].y +            \
               x0.w * W[3].y + x1.x * W[4].y + x1.y * W[5].y +            \
               x1.z * W[6].y + x1.w * W[7].y;                             \
    }                                                                     \
  }

// ---------------- GEMM1 k-split engine ----------------
// threads: 4 k-quarters (q=tid>>8) x 256 col-pairs; zero weight redundancy.
// chunk=8, ping-pong wA/wB register sets, loads issued a half-chunk ahead.
template <int PC>
__device__ void g1ks(const float* __restrict__ Abuf, float* __restrict__ part,
                     const int tid, const float* __restrict__ W1) {
  const int q = tid >> 8;
  const int c0 = (tid & 255) << 1;
  const float* Wp = W1 + (size_t)(q * 128) * NH + c0;
  const float* Ar = Abuf + q * 128;
  float a0[PC], a1[PC];
#pragma unroll
  for (int r = 0; r < PC; ++r) { a0[r] = 0.f; a1[r] = 0.f; }
  float2 wA[8], wB[8];
  LD8(wA, 0, NH);
#pragma unroll 2
  for (int kc = 0; kc < 128; kc += 16) {
    LD8(wB, kc + 8, NH);
    G_HALF(wA, kc, PC, Ar);
    if (kc + 16 < 128) LD8(wA, kc + 16, NH);
    G_HALF(wB, kc + 8, PC, Ar);
  }
#pragma unroll
  for (int r = 0; r < PC; ++r)
    *(float2*)&part[(q * PC + r) * 512 + c0] = make_float2(a0[r], a1[r]);
}

// reduce 4 quarters -> relu(+bias (+emb[bit])) -> hid rows [0,PC)
template <int PC>
__device__ void g1red(const float* __restrict__ part, float* __restrict__ hid,
                      const int tid, const float* __restrict__ b1,
                      const int isBn, const float* __restrict__ embS,
                      const int* __restrict__ bitR) {
  for (int i = tid; i < PC * 256; i += NT) {
    const int r = i >> 8, c0 = (i & 255) << 1;
    float2 s = *(const float2*)(b1 + c0);
#pragma unroll
    for (int qq = 0; qq < 4; ++qq) {
      const float2 p = *(const float2*)&part[(qq * PC + r) * 512 + c0];
      s.x += p.x; s.y += p.y;
    }
    if (isBn) {
      const float2 e = *(const float2*)&embS[bitR[r] * 512 + c0];
      s.x += e.x; s.y += e.y;
    }
    *(float2*)&hid[r * 512 + c0] = make_float2(fmaxf(s.x, 0.f), fmaxf(s.y, 0.f));
  }
}

// reduce + expand both bit-variants -> hid rows [base + 2r + b]
template <int R>
__device__ void g1redspec(const float* __restrict__ part, float* __restrict__ hid,
                          const int base, const int tid,
                          const float* __restrict__ b1,
                          const float* __restrict__ embS) {
  for (int i = tid; i < R * 256; i += NT) {
    const int r = i >> 8, c0 = (i & 255) << 1;
    float2 s = *(const float2*)(b1 + c0);
#pragma unroll
    for (int qq = 0; qq < 4; ++qq) {
      const float2 p = *(const float2*)&part[(qq * R + r) * 512 + c0];
      s.x += p.x; s.y += p.y;
    }
    const float2 e0 = *(const float2*)&embS[c0];
    const float2 e1 = *(const float2*)&embS[512 + c0];
    *(float2*)&hid[(base + 2 * r) * 512 + c0] =
        make_float2(fmaxf(s.x + e0.x, 0.f), fmaxf(s.y + e0.y, 0.f));
    *(float2*)&hid[(base + 2 * r + 1) * 512 + c0] =
        make_float2(fmaxf(s.x + e1.x, 0.f), fmaxf(s.y + e1.y, 0.f));
  }
}

// ---------------- GEMM2 k-split engine ----------------
// threads: 8 k-eighths (q=tid>>7) x 128 col-pairs; zero redundancy.
template <int RT>
__device__ void g2ks(const float* __restrict__ hid, const int hidBase,
                     float* __restrict__ part, const int tid,
                     const float* __restrict__ W2) {
  const int q = tid >> 7;
  const int c0 = (tid & 127) << 1;
  const float* Wp = W2 + (size_t)(q * 64) * ND + c0;
  const float* Hr = hid + hidBase * 512 + q * 64;
  float a0[RT], a1[RT];
#pragma unroll
  for (int r = 0; r < RT; ++r) { a0[r] = 0.f; a1[r] = 0.f; }
  float2 wA[8], wB[8];
  LD8(wA, 0, ND);
#pragma unroll 2
  for (int kc = 0; kc < 64; kc += 16) {
    LD8(wB, kc + 8, ND);
    G_HALF(wA, kc, RT, Hr);
    if (kc + 16 < 64) LD8(wA, kc + 16, ND);
    G_HALF(wB, kc + 8, RT, Hr);
  }
#pragma unroll
  for (int r = 0; r < RT; ++r)
    *(float2*)&part[(q * RT + r) * 256 + c0] = make_float2(a0[r], a1[r]);
}

template <int RT>
__device__ void g2red(const float* __restrict__ part, const int tid,
                      const float* __restrict__ b2,
                      float* const* __restrict__ rowDst) {
  for (int i = tid; i < RT * 128; i += NT) {
    const int r = i >> 7, c0 = (i & 127) << 1;
    float2 s = *(const float2*)(b2 + c0);
#pragma unroll
    for (int qq = 0; qq < 8; ++qq) {
      const float2 p = *(const float2*)&part[(qq * RT + r) * 256 + c0];
      s.x += p.x; s.y += p.y;
    }
    *(float2*)(rowDst[r] + c0) = s;
  }
}

__global__ __launch_bounds__(NT, 4) void sc_quad(
    const int* __restrict__ info_bits, const float* __restrict__ rv,
    const int* __restrict__ info_set,
    const float* __restrict__ obs_emb, const float* __restrict__ label_emb,
    const float* __restrict__ cnW1, const float* __restrict__ cnb1,
    const float* __restrict__ cnW2, const float* __restrict__ cnb2,
    const float* __restrict__ bnW1, const float* __restrict__ bnb1,
    const float* __restrict__ bnW2, const float* __restrict__ bnb2,
    const float* __restrict__ llrW, const float* __restrict__ llrb,
    float* __restrict__ out, float* __restrict__ ws) {
  __shared__ float A[4096];       // <=8 staged input rows
  __shared__ float part[20480];   // k-split partials (G1<=16384, G2<=20480)
  __shared__ float hid[8192];     // <=16 hidden rows
  __shared__ float embS[1024];    // label_emb[bit] @ bnW1[512:768]
  __shared__ float rowBuf[256];   // uniform-pass single output row
  __shared__ float* rowDst[16];
  __shared__ int fmap[256];
  __shared__ int curS[256], nxtS[256];
  __shared__ float red[8];
  __shared__ int bitR[8];
  __shared__ int qbS[4];

  const int tid = threadIdx.x, b = blockIdx.x;
  float* wsb = ws + (size_t)b * BPB;
  float* E = wsb;
  float* sp6 = wsb + SP6O;
  float* S1 = wsb + S1O;
  float* S2 = wsb + S2O;
  float* S3 = wsb + S3O;
  int* Lb = (int*)(wsb + LOFFI);
  const float* obs2 = obs_emb + 2 * ND;

  // ---- init: embC + fmap ----
  {
    const int bit = tid >> 9, col = tid & 511;
    float s = 0.f;
#pragma unroll 4
    for (int j = 0; j < ND; ++j)
      s += label_emb[bit * ND + j] * bnW1[(size_t)(NH + j) * NH + col];
    embS[bit * 512 + col] = s;
  }
  if (tid < 256) fmap[tid] = -1;
  __syncthreads();
  if (tid < NK) fmap[info_set[tid]] = tid;
  __syncthreads();

  auto stageA = [&](const float* Ed, int p0, int R) {
    const int n4 = R * 128;
    float4* A4 = (float4*)A;
    if (Ed) {
      const float4* s4 = (const float4*)(Ed + (size_t)(2 * p0) * ND);
      for (int i = tid; i < n4; i += NT) A4[i] = s4[i];
    } else {
      const float4* o4 = (const float4*)obs2;
      for (int i = tid; i < n4; i += NT) A4[i] = o4[i & 63];
    }
  };

  auto plainPass = [&](int d, int isBn) {
    const int P = 1 << (7 - d);
    const float* W1 = isBn ? bnW1 : cnW1;
    const float* B1 = isBn ? bnb1 : cnb1;
    const float* W2 = isBn ? bnW2 : cnW2;
    const float* B2 = isBn ? bnb2 : cnb2;
    const float* Ed = (d == 0) ? nullptr : E + (size_t)loff(d) * ND;
    float* dstE = E + (size_t)loff(d + 1) * ND;
    const int PC = P >= 8 ? 8 : 4;  // d<=5 -> P>=4
    for (int p0 = 0; p0 < P; p0 += PC) {
      stageA(Ed, p0, PC);
      if (isBn && tid < PC) bitR[tid] = Lb[loff(d + 1) + p0 + tid];
      if (tid < PC) rowDst[tid] = dstE + (size_t)(p0 + tid) * ND;
      __syncthreads();
      if (PC == 8) {
        g1ks<8>(A, part, tid, W1); __syncthreads();
        g1red<8>(part, hid, tid, B1, isBn, embS, bitR); __syncthreads();
        g2ks<8>(hid, 0, part, tid, W2); __syncthreads();
        g2red<8>(part, tid, B2, rowDst); __syncthreads();
      } else {
        g1ks<4>(A, part, tid, W1); __syncthreads();
        g1red<4>(part, hid, tid, B1, isBn, embS, bitR); __syncthreads();
        g2ks<4>(hid, 0, part, tid, W2); __syncthreads();
        g2red<4>(part, tid, B2, rowDst); __syncthreads();
      }
    }
  };

  // uniform initial-descent pass: all rows of E_d are identical -> compute 1
  // row, broadcast-store to all P positions of E_{d+1}.
  auto uniPass = [&](int d) {
    const int P = 1 << (7 - d);
    const float* Ed = (d == 0) ? nullptr : E + (size_t)loff(d) * ND;
    float* dstE = E + (size_t)loff(d + 1) * ND;
    stageA(Ed, 0, 1);
    if (tid == 0) rowDst[0] = rowBuf;
    __syncthreads();
    g1ks<1>(A, part, tid, cnW1); __syncthreads();
    g1red<1>(part, hid, tid, cnb1, 0, embS, bitR); __syncthreads();
    g2ks<1>(hid, 0, part, tid, cnW2); __syncthreads();
    g2red<1>(part, tid, cnb2, rowDst); __syncthreads();
    for (int i = tid; i < P * 256; i += NT) dstE[i] = rowBuf[i & 255];
    __syncthreads();
  };

  // depth-6 pair: cn6 (2 rows -> E7) + bn6 spec (2 rows x 2 bits -> sp6[0..3])
  auto pair6 = [&]() {
    stageA(E + (size_t)loff(6) * ND, 0, 2);
    if (tid < 2) rowDst[tid] = E + (size_t)(252 + tid) * ND;
    __syncthreads();
    g1ks<2>(A, part, tid, cnW1); __syncthreads();
    g1red<2>(part, hid, tid, cnb1, 0, embS, bitR); __syncthreads();
    g2ks<2>(hid, 0, part, tid, cnW2); __syncthreads();
    g2red<2>(part, tid, cnb2, rowDst); __syncthreads();
    g1ks<2>(A, part, tid, bnW1); __syncthreads();
    g1redspec<2>(part, hid, 2, tid, bnb1, embS); __syncthreads();
    g2ks<4>(hid, 2, part, tid, bnW2);
    if (tid < 4) rowDst[tid] = sp6 + (size_t)tid * ND;
    __syncthreads();
    g2red<4>(part, tid, bnb2, rowDst); __syncthreads();
  };

  // depth-7 combined: 5 A rows -> cn {E8, S2[0..3]} + bn-spec {S1[0..1], S3[0..7]}
  auto comb = [&]() {
    for (int i = tid; i < 5 * 128; i += NT) {
      const int r = i >> 7, k = (i & 127) << 2;
      const int h = k >> 8;
      const float* src;
      if (r == 0) src = E + (size_t)(252 + h) * ND;
      else {
        const int cc = r - 1;
        const int bit = (h == 0) ? (cc >> 1) : (cc & 1);
        src = sp6 + (size_t)(h * 2 + bit) * ND;
      }
      *(float4*)&A[r * 512 + k] = *(const float4*)&src[k & 255];
    }
    __syncthreads();
    g1ks<5>(A, part, tid, cnW1); __syncthreads();
    g1red<5>(part, hid, tid, cnb1, 0, embS, bitR); __syncthreads();
    g2ks<5>(hid, 0, part, tid, cnW2);
    if (tid < 5) rowDst[tid] = (tid == 0) ? (E + (size_t)254 * ND)
                                          : (S2 + (size_t)(tid - 1) * ND);
    __syncthreads();
    g2red<5>(part, tid, cnb2, rowDst); __syncthreads();
    g1ks<5>(A, part, tid, bnW1); __syncthreads();
    g1redspec<5>(part, hid, 5, tid, bnb1, embS); __syncthreads();
    g2ks<10>(hid, 5, part, tid, bnW2);
    if (tid < 10) rowDst[tid] = (tid < 2) ? (S1 + (size_t)tid * ND)
                                          : (S3 + (size_t)(tid - 2) * ND);
    __syncthreads();
    g2red<10>(part, tid, bnb2, rowDst); __syncthreads();
  };

  auto leaf = [&](int off) {
    const int ph = off & 3;
    const float* src;
    if (ph == 0) src = E + (size_t)254 * ND;
    else if (ph == 1) src = S1 + (size_t)qbS[0] * ND;
    else {
      const int cidx = 2 * (qbS[0] ^ qbS[1]) + qbS[1];
      src = (ph == 2) ? (S2 + (size_t)cidx * ND)
                      : (S3 + (size_t)(2 * cidx + qbS[2]) * ND);
    }
    if (tid < 256) {
      const float ev = src[tid];
      float v0 = ev * llrW[2 * tid];
      float v1 = ev * llrW[2 * tid + 1];
#pragma unroll
      for (int o = 32; o > 0; o >>= 1) {
        v0 += __shfl_down(v0, o);
        v1 += __shfl_down(v1, o);
      }
      if ((tid & 63) == 0) {
        red[tid >> 6] = v0;
        red[4 + (tid >> 6)] = v1;
      }
    }
    __syncthreads();
    if (tid == 0) {
      const float l0 = red[0] + red[1] + red[2] + red[3] + llrb[0];
      const float l1 = red[4] + red[5] + red[6] + red[7] + llrb[1];
      const float m = fmaxf(l0, l1);
      const float e0 = expf(l0 - m), e1 = expf(l1 - m);
      const float s = e0 + e1;
      const float p0 = e0 / s, p1 = e1 / s;
      const int hard = (rv[b * NN + off] > p0) ? 1 : 0;
      const int fidx = fmap[off];
      const int fval = (fidx >= 0) ? info_bits[b * NK + fidx] : 2;
      const int xb = (fval == 2) ? hard : fval;
      out[OUT_F + b * NN + off] = (fidx >= 0) ? 2.0f : (float)xb;
      out[OUT_U + b * NN + off] = (float)xb;
      out[OUT_P + (b * NN + off) * 2 + 0] = p0;
      out[OUT_P + (b * NN + off) * 2 + 1] = p1;
      curS[0] = xb;
      qbS[ph] = xb;
    }
    __syncthreads();
    int* cur = curS;
    int* nxt = nxtS;
    int len = 1, lev = 8, idx = off;
    while (idx & 1) {
      if (tid < len) {
        const int c = cur[tid];
        nxt[2 * tid] = Lb[loff(lev) + tid] ^ c;
        nxt[2 * tid + 1] = c;
      }
      __syncthreads();
      int* t = cur; cur = nxt; nxt = t;
      len <<= 1; idx >>= 1; --lev;
    }
    if (lev > 0) {
      if (tid < len) Lb[loff(lev) + tid] = cur[tid];
    } else {
      if (tid < 256) out[OUT_X + b * NN + tid] = (float)cur[tid];
    }
    __syncthreads();
  };

  // ---- initial descent (uniform rows -> 1-row passes) ----
  for (int d = 0; d <= 5; ++d) uniPass(d);
  pair6();
  comb();

  // ---- leaf loop ----
  for (int off = 0; off < NN; ++off) {
    leaf(off);
    if (off == NN - 1) break;
    const int t = off + 1;
    const int z = __ffs(t) - 1;
    if (z <= 1) continue;  // inside a quad: everything pre-speculated
    const int dbn = 7 - z;  // <= 5
    plainPass(dbn, 1);
    for (int d = dbn + 1; d <= 5; ++d) plainPass(d, 0);
    pair6();
    comb();
  }
}

extern "C" void kernel_launch(void* const* d_in, const int* in_sizes, int n_in,
                              void* d_out, int out_size, void* d_ws, size_t ws_size,
                              hipStream_t stream) {
  const int*   info_bits = (const int*)d_in[0];
  const float* rv        = (const float*)d_in[1];
  const int*   info_set  = (const int*)d_in[2];
  const float* obs_emb   = (const float*)d_in[3];
  const float* label_emb = (const float*)d_in[4];
  const float* cnW1      = (const float*)d_in[5];
  const float* cnb1      = (const float*)d_in[6];
  const float* cnW2      = (const float*)d_in[7];
  const float* cnb2      = (const float*)d_in[8];
  const float* bnW1      = (const float*)d_in[9];
  const float* bnb1      = (const float*)d_in[10];
  const float* bnW2      = (const float*)d_in[11];
  const float* bnb2      = (const float*)d_in[12];
  const float* llrW      = (const float*)d_in[13];
  const float* llrb      = (const float*)d_in[14];

  float* out = (float*)d_out;
  float* ws  = (float*)d_ws;

  sc_quad<<<dim3(NB), dim3(NT), 0, stream>>>(
      info_bits, rv, info_set, obs_emb, label_emb,
      cnW1, cnb1, cnW2, cnb2, bnW1, bnb1, bnW2, bnb2,
      llrW, llrb, out, ws);
}

// Round 11
// 32657.040 us; speedup vs baseline: 3.4959x; 3.4959x over previous
//
#include <hip/hip_runtime.h>
#include <math.h>

#define NB 256
#define NN 256
#define NK 128
#define ND 256
#define NH 512
#define NT 1024

// output layout (floats): x | f_out | u | p_u
#define OUT_X 0
#define OUT_F 65536
#define OUT_U 131072
#define OUT_P 196608

// per-batch ws float offsets
#define EPB   65280            // E levels 1..8 (255*256)
#define SP6O  EPB              // bn6 spec: 4*256
#define S1O   (SP6O + 1024)    // 2*256
#define S2O   (S1O + 512)      // 4*256
#define S3O   (S2O + 1024)     // 8*256
#define LOFFI (S3O + 2048)     // 256 ints (decision-bit slabs)
#define BPB   (LOFFI + 256)

__host__ __device__ __forceinline__ int loff(int d) { return 256 - (1 << (9 - d)); }

// 8 consecutive weight rows (col pair) in NAMED fields -> guaranteed registers.
struct W8 {
  float2 w0, w1, w2, w3, w4, w5, w6, w7;
};

__device__ __forceinline__ W8 ld8(const float* __restrict__ Wp, int k, int ldw) {
  W8 r;
  const float* q = Wp + (size_t)k * ldw;
  r.w0 = *(const float2*)(q);
  r.w1 = *(const float2*)(q + ldw);
  r.w2 = *(const float2*)(q + 2 * ldw);
  r.w3 = *(const float2*)(q + 3 * ldw);
  r.w4 = *(const float2*)(q + 4 * ldw);
  r.w5 = *(const float2*)(q + 5 * ldw);
  r.w6 = *(const float2*)(q + 6 * ldw);
  r.w7 = *(const float2*)(q + 7 * ldw);
  return r;
}

template <int R>
__device__ __forceinline__ void fma8(const W8& w, const float* __restrict__ Ar,
                                     int off, float* a0, float* a1) {
#pragma unroll
  for (int r = 0; r < R; ++r) {
    const float4 x0 = *(const float4*)(Ar + r * 512 + off);
    const float4 x1 = *(const float4*)(Ar + r * 512 + off + 4);
    a0[r] += x0.x * w.w0.x + x0.y * w.w1.x + x0.z * w.w2.x + x0.w * w.w3.x +
             x1.x * w.w4.x + x1.y * w.w5.x + x1.z * w.w6.x + x1.w * w.w7.x;
    a1[r] += x0.x * w.w0.y + x0.y * w.w1.y + x0.z * w.w2.y + x0.w * w.w3.y +
             x1.x * w.w4.y + x1.y * w.w5.y + x1.z * w.w6.y + x1.w * w.w7.y;
  }
}

// ---------------- GEMM1 k-split engine ----------------
// threads: 4 k-quarters (q=tid>>8) x 256 col-pairs; zero weight redundancy.
template <int PC>
__device__ void g1ks(const float* __restrict__ Abuf, float* __restrict__ part,
                     const int tid, const float* __restrict__ W1) {
  const int q = tid >> 8;
  const int c0 = (tid & 255) << 1;
  const float* Wp = W1 + (size_t)(q * 128) * NH + c0;
  const float* Ar = Abuf + q * 128;
  float a0[PC], a1[PC];
#pragma unroll
  for (int r = 0; r < PC; ++r) { a0[r] = 0.f; a1[r] = 0.f; }
  W8 cur = ld8(Wp, 0, NH);
  for (int kc = 0; kc < 128; kc += 16) {
    W8 nxt = ld8(Wp, kc + 8, NH);
    fma8<PC>(cur, Ar, kc, a0, a1);
    if (kc + 16 < 128) cur = ld8(Wp, kc + 16, NH);
    fma8<PC>(nxt, Ar, kc + 8, a0, a1);
  }
#pragma unroll
  for (int r = 0; r < PC; ++r)
    *(float2*)&part[(q * PC + r) * 512 + c0] = make_float2(a0[r], a1[r]);
}

// reduce 4 quarters -> relu(+bias (+emb[bit])) -> hid rows [0,PC)
template <int PC>
__device__ void g1red(const float* __restrict__ part, float* __restrict__ hid,
                      const int tid, const float* __restrict__ b1,
                      const int isBn, const float* __restrict__ embS,
                      const int* __restrict__ bitR) {
  for (int i = tid; i < PC * 256; i += NT) {
    const int r = i >> 8, c0 = (i & 255) << 1;
    float2 s = *(const float2*)(b1 + c0);
#pragma unroll
    for (int qq = 0; qq < 4; ++qq) {
      const float2 p = *(const float2*)&part[(qq * PC + r) * 512 + c0];
      s.x += p.x; s.y += p.y;
    }
    if (isBn) {
      const float2 e = *(const float2*)&embS[bitR[r] * 512 + c0];
      s.x += e.x; s.y += e.y;
    }
    *(float2*)&hid[r * 512 + c0] = make_float2(fmaxf(s.x, 0.f), fmaxf(s.y, 0.f));
  }
}

// reduce + expand both bit-variants -> hid rows [base + 2r + b]
template <int R>
__device__ void g1redspec(const float* __restrict__ part, float* __restrict__ hid,
                          const int base, const int tid,
                          const float* __restrict__ b1,
                          const float* __restrict__ embS) {
  for (int i = tid; i < R * 256; i += NT) {
    const int r = i >> 8, c0 = (i & 255) << 1;
    float2 s = *(const float2*)(b1 + c0);
#pragma unroll
    for (int qq = 0; qq < 4; ++qq) {
      const float2 p = *(const float2*)&part[(qq * R + r) * 512 + c0];
      s.x += p.x; s.y += p.y;
    }
    const float2 e0 = *(const float2*)&embS[c0];
    const float2 e1 = *(const float2*)&embS[512 + c0];
    *(float2*)&hid[(base + 2 * r) * 512 + c0] =
        make_float2(fmaxf(s.x + e0.x, 0.f), fmaxf(s.y + e0.y, 0.f));
    *(float2*)&hid[(base + 2 * r + 1) * 512 + c0] =
        make_float2(fmaxf(s.x + e1.x, 0.f), fmaxf(s.y + e1.y, 0.f));
  }
}

// ---------------- GEMM2 k-split engine ----------------
// threads: 8 k-eighths (q=tid>>7) x 128 col-pairs; zero redundancy.
template <int RT>
__device__ void g2ks(const float* __restrict__ hid, const int hidBase,
                     float* __restrict__ part, const int tid,
                     const float* __restrict__ W2) {
  const int q = tid >> 7;
  const int c0 = (tid & 127) << 1;
  const float* Wp = W2 + (size_t)(q * 64) * ND + c0;
  const float* Hr = hid + hidBase * 512 + q * 64;
  float a0[RT], a1[RT];
#pragma unroll
  for (int r = 0; r < RT; ++r) { a0[r] = 0.f; a1[r] = 0.f; }
  W8 cur = ld8(Wp, 0, ND);
  for (int kc = 0; kc < 64; kc += 16) {
    W8 nxt = ld8(Wp, kc + 8, ND);
    fma8<RT>(cur, Hr, kc, a0, a1);
    if (kc + 16 < 64) cur = ld8(Wp, kc + 16, ND);
    fma8<RT>(nxt, Hr, kc + 8, a0, a1);
  }
#pragma unroll
  for (int r = 0; r < RT; ++r)
    *(float2*)&part[(q * RT + r) * 256 + c0] = make_float2(a0[r], a1[r]);
}

template <int RT>
__device__ void g2red(const float* __restrict__ part, const int tid,
                      const float* __restrict__ b2,
                      float* const* __restrict__ rowDst) {
  for (int i = tid; i < RT * 128; i += NT) {
    const int r = i >> 7, c0 = (i & 127) << 1;
    float2 s = *(const float2*)(b2 + c0);
#pragma unroll
    for (int qq = 0; qq < 8; ++qq) {
      const float2 p = *(const float2*)&part[(qq * RT + r) * 256 + c0];
      s.x += p.x; s.y += p.y;
    }
    *(float2*)(rowDst[r] + c0) = s;
  }
}

__global__ __launch_bounds__(NT, 4) void sc_quad(
    const int* __restrict__ info_bits, const float* __restrict__ rv,
    const int* __restrict__ info_set,
    const float* __restrict__ obs_emb, const float* __restrict__ label_emb,
    const float* __restrict__ cnW1, const float* __restrict__ cnb1,
    const float* __restrict__ cnW2, const float* __restrict__ cnb2,
    const float* __restrict__ bnW1, const float* __restrict__ bnb1,
    const float* __restrict__ bnW2, const float* __restrict__ bnb2,
    const float* __restrict__ llrW, const float* __restrict__ llrb,
    float* __restrict__ out, float* __restrict__ ws) {
  __shared__ float A[4096];       // <=8 staged input rows
  __shared__ float part[20480];   // k-split partials (G1<=16384, G2<=20480)
  __shared__ float hid[8192];     // <=16 hidden rows
  __shared__ float embS[1024];    // label_emb[bit] @ bnW1[512:768]
  __shared__ float rowBuf[256];   // uniform-pass single output row
  __shared__ float* rowDst[16];
  __shared__ int fmap[256];
  __shared__ int curS[256], nxtS[256];
  __shared__ float red[8];
  __shared__ int bitR[8];
  __shared__ int qbS[4];

  const int tid = threadIdx.x, b = blockIdx.x;
  float* wsb = ws + (size_t)b * BPB;
  float* E = wsb;
  float* sp6 = wsb + SP6O;
  float* S1 = wsb + S1O;
  float* S2 = wsb + S2O;
  float* S3 = wsb + S3O;
  int* Lb = (int*)(wsb + LOFFI);
  const float* obs2 = obs_emb + 2 * ND;

  // ---- init: embC + fmap ----
  {
    const int bit = tid >> 9, col = tid & 511;
    float s = 0.f;
#pragma unroll 4
    for (int j = 0; j < ND; ++j)
      s += label_emb[bit * ND + j] * bnW1[(size_t)(NH + j) * NH + col];
    embS[bit * 512 + col] = s;
  }
  if (tid < 256) fmap[tid] = -1;
  __syncthreads();
  if (tid < NK) fmap[info_set[tid]] = tid;
  __syncthreads();

  auto stageA = [&](const float* Ed, int p0, int R) {
    const int n4 = R * 128;
    float4* A4 = (float4*)A;
    if (Ed) {
      const float4* s4 = (const float4*)(Ed + (size_t)(2 * p0) * ND);
      for (int i = tid; i < n4; i += NT) A4[i] = s4[i];
    } else {
      const float4* o4 = (const float4*)obs2;
      for (int i = tid; i < n4; i += NT) A4[i] = o4[i & 63];
    }
  };

  auto plainPass = [&](int d, int isBn) {
    const int P = 1 << (7 - d);
    const float* W1 = isBn ? bnW1 : cnW1;
    const float* B1 = isBn ? bnb1 : cnb1;
    const float* W2 = isBn ? bnW2 : cnW2;
    const float* B2 = isBn ? bnb2 : cnb2;
    const float* Ed = (d == 0) ? nullptr : E + (size_t)loff(d) * ND;
    float* dstE = E + (size_t)loff(d + 1) * ND;
    const int PC = P >= 8 ? 8 : 4;  // d<=5 -> P>=4
    for (int p0 = 0; p0 < P; p0 += PC) {
      stageA(Ed, p0, PC);
      if (isBn && tid < PC) bitR[tid] = Lb[loff(d + 1) + p0 + tid];
      if (tid < PC) rowDst[tid] = dstE + (size_t)(p0 + tid) * ND;
      __syncthreads();
      if (PC == 8) {
        g1ks<8>(A, part, tid, W1); __syncthreads();
        g1red<8>(part, hid, tid, B1, isBn, embS, bitR); __syncthreads();
        g2ks<8>(hid, 0, part, tid, W2); __syncthreads();
        g2red<8>(part, tid, B2, rowDst); __syncthreads();
      } else {
        g1ks<4>(A, part, tid, W1); __syncthreads();
        g1red<4>(part, hid, tid, B1, isBn, embS, bitR); __syncthreads();
        g2ks<4>(hid, 0, part, tid, W2); __syncthreads();
        g2red<4>(part, tid, B2, rowDst); __syncthreads();
      }
    }
  };

  // uniform initial-descent pass: all rows of E_d are identical -> compute 1
  // row, broadcast-store to all P positions of E_{d+1}. (verified round 10)
  auto uniPass = [&](int d) {
    const int P = 1 << (7 - d);
    const float* Ed = (d == 0) ? nullptr : E + (size_t)loff(d) * ND;
    float* dstE = E + (size_t)loff(d + 1) * ND;
    stageA(Ed, 0, 1);
    if (tid == 0) rowDst[0] = rowBuf;
    __syncthreads();
    g1ks<1>(A, part, tid, cnW1); __syncthreads();
    g1red<1>(part, hid, tid, cnb1, 0, embS, bitR); __syncthreads();
    g2ks<1>(hid, 0, part, tid, cnW2); __syncthreads();
    g2red<1>(part, tid, cnb2, rowDst); __syncthreads();
    for (int i = tid; i < P * 256; i += NT) dstE[i] = rowBuf[i & 255];
    __syncthreads();
  };

  // depth-6 pair: cn6 (2 rows -> E7) + bn6 spec (2 rows x 2 bits -> sp6[0..3])
  auto pair6 = [&]() {
    stageA(E + (size_t)loff(6) * ND, 0, 2);
    if (tid < 2) rowDst[tid] = E + (size_t)(252 + tid) * ND;
    __syncthreads();
    g1ks<2>(A, part, tid, cnW1); __syncthreads();
    g1red<2>(part, hid, tid, cnb1, 0, embS, bitR); __syncthreads();
    g2ks<2>(hid, 0, part, tid, cnW2); __syncthreads();
    g2red<2>(part, tid, cnb2, rowDst); __syncthreads();
    g1ks<2>(A, part, tid, bnW1); __syncthreads();
    g1redspec<2>(part, hid, 2, tid, bnb1, embS); __syncthreads();
    g2ks<4>(hid, 2, part, tid, bnW2);
    if (tid < 4) rowDst[tid] = sp6 + (size_t)tid * ND;
    __syncthreads();
    g2red<4>(part, tid, bnb2, rowDst); __syncthreads();
  };

  // depth-7 combined: 5 A rows -> cn {E8, S2[0..3]} + bn-spec {S1[0..1], S3[0..7]}
  auto comb = [&]() {
    for (int i = tid; i < 5 * 128; i += NT) {
      const int r = i >> 7, k = (i & 127) << 2;
      const int h = k >> 8;
      const float* src;
      if (r == 0) src = E + (size_t)(252 + h) * ND;
      else {
        const int cc = r - 1;
        const int bit = (h == 0) ? (cc >> 1) : (cc & 1);
        src = sp6 + (size_t)(h * 2 + bit) * ND;
      }
      *(float4*)&A[r * 512 + k] = *(const float4*)&src[k & 255];
    }
    __syncthreads();
    g1ks<5>(A, part, tid, cnW1); __syncthreads();
    g1red<5>(part, hid, tid, cnb1, 0, embS, bitR); __syncthreads();
    g2ks<5>(hid, 0, part, tid, cnW2);
    if (tid < 5) rowDst[tid] = (tid == 0) ? (E + (size_t)254 * ND)
                                          : (S2 + (size_t)(tid - 1) * ND);
    __syncthreads();
    g2red<5>(part, tid, cnb2, rowDst); __syncthreads();
    g1ks<5>(A, part, tid, bnW1); __syncthreads();
    g1redspec<5>(part, hid, 5, tid, bnb1, embS); __syncthreads();
    g2ks<10>(hid, 5, part, tid, bnW2);
    if (tid < 10) rowDst[tid] = (tid < 2) ? (S1 + (size_t)tid * ND)
                                          : (S3 + (size_t)(tid - 2) * ND);
    __syncthreads();
    g2red<10>(part, tid, bnb2, rowDst); __syncthreads();
  };

  auto leaf = [&](int off) {
    const int ph = off & 3;
    const float* src;
    if (ph == 0) src = E + (size_t)254 * ND;
    else if (ph == 1) src = S1 + (size_t)qbS[0] * ND;
    else {
      const int cidx = 2 * (qbS[0] ^ qbS[1]) + qbS[1];
      src = (ph == 2) ? (S2 + (size_t)cidx * ND)
                      : (S3 + (size_t)(2 * cidx + qbS[2]) * ND);
    }
    if (tid < 256) {
      const float ev = src[tid];
      float v0 = ev * llrW[2 * tid];
      float v1 = ev * llrW[2 * tid + 1];
#pragma unroll
      for (int o = 32; o > 0; o >>= 1) {
        v0 += __shfl_down(v0, o);
        v1 += __shfl_down(v1, o);
      }
      if ((tid & 63) == 0) {
        red[tid >> 6] = v0;
        red[4 + (tid >> 6)] = v1;
      }
    }
    __syncthreads();
    if (tid == 0) {
      const float l0 = red[0] + red[1] + red[2] + red[3] + llrb[0];
      const float l1 = red[4] + red[5] + red[6] + red[7] + llrb[1];
      const float m = fmaxf(l0, l1);
      const float e0 = expf(l0 - m), e1 = expf(l1 - m);
      const float s = e0 + e1;
      const float p0 = e0 / s, p1 = e1 / s;
      const int hard = (rv[b * NN + off] > p0) ? 1 : 0;
      const int fidx = fmap[off];
      const int fval = (fidx >= 0) ? info_bits[b * NK + fidx] : 2;
      const int xb = (fval == 2) ? hard : fval;
      out[OUT_F + b * NN + off] = (fidx >= 0) ? 2.0f : (float)xb;
      out[OUT_U + b * NN + off] = (float)xb;
      out[OUT_P + (b * NN + off) * 2 + 0] = p0;
      out[OUT_P + (b * NN + off) * 2 + 1] = p1;
      curS[0] = xb;
      qbS[ph] = xb;
    }
    __syncthreads();
    int* cur = curS;
    int* nxt = nxtS;
    int len = 1, lev = 8, idx = off;
    while (idx & 1) {
      if (tid < len) {
        const int c = cur[tid];
        nxt[2 * tid] = Lb[loff(lev) + tid] ^ c;
        nxt[2 * tid + 1] = c;
      }
      __syncthreads();
      int* t = cur; cur = nxt; nxt = t;
      len <<= 1; idx >>= 1; --lev;
    }
    if (lev > 0) {
      if (tid < len) Lb[loff(lev) + tid] = cur[tid];
    } else {
      if (tid < 256) out[OUT_X + b * NN + tid] = (float)cur[tid];
    }
    __syncthreads();
  };

  // ---- initial descent (uniform rows -> 1-row passes) ----
  for (int d = 0; d <= 5; ++d) uniPass(d);
  pair6();
  comb();

  // ---- leaf loop ----
  for (int off = 0; off < NN; ++off) {
    leaf(off);
    if (off == NN - 1) break;
    const int t = off + 1;
    const int z = __ffs(t) - 1;
    if (z <= 1) continue;  // inside a quad: everything pre-speculated
    const int dbn = 7 - z;  // <= 5
    plainPass(dbn, 1);
    for (int d = dbn + 1; d <= 5; ++d) plainPass(d, 0);
    pair6();
    comb();
  }
}

extern "C" void kernel_launch(void* const* d_in, const int* in_sizes, int n_in,
                              void* d_out, int out_size, void* d_ws, size_t ws_size,
                              hipStream_t stream) {
  const int*   info_bits = (const int*)d_in[0];
  const float* rv        = (const float*)d_in[1];
  const int*   info_set  = (const int*)d_in[2];
  const float* obs_emb   = (const float*)d_in[3];
  const float* label_emb = (const float*)d_in[4];
  const float* cnW1      = (const float*)d_in[5];
  const float* cnb1      = (const float*)d_in[6];
  const float* cnW2      = (const float*)d_in[7];
  const float* cnb2      = (const float*)d_in[8];
  const float* bnW1      = (const float*)d_in[9];
  const float* bnb1      = (const float*)d_in[10];
  const float* bnW2      = (const float*)d_in[11];
  const float* bnb2      = (const float*)d_in[12];
  const float* llrW      = (const float*)d_in[13];
  const float* llrb      = (const float*)d_in[14];

  float* out = (float*)d_out;
  float* ws  = (float*)d_ws;

  sc_quad<<<dim3(NB), dim3(NT), 0, stream>>>(
      info_bits, rv, info_set, obs_emb, label_emb,
      cnW1, cnb1, cnW2, cnb2, bnW1, bnb1, bnW2, bnb2,
      llrW, llrb, out, ws);
}

// Round 12
// 10794.991 us; speedup vs baseline: 10.5759x; 3.0252x over previous
//
#include <hip/hip_runtime.h>
#include <math.h>

#define NB 256
#define NN 256
#define NK 128
#define ND 256
#define NH 512
#define NT 1024

// output layout (floats): x | f_out | u | p_u
#define OUT_X 0
#define OUT_F 65536
#define OUT_U 131072
#define OUT_P 196608

// per-batch ws float offsets
#define EPB   65280            // E levels 1..8 (255*256)
#define SP6O  EPB              // bn6 spec: 4*256
#define S1O   (SP6O + 1024)    // 2*256
#define S2O   (S1O + 512)      // 4*256
#define S3O   (S2O + 1024)     // 8*256
#define LOFFI (S3O + 2048)     // 256 ints (decision-bit slabs)
#define BPB   (LOFFI + 256)

__host__ __device__ __forceinline__ int loff(int d) { return 256 - (1 << (9 - d)); }

// ================= legacy engines (R9, proven; used for PC=8 / RT=10) =======
template <int PC>
__device__ void g1ks(const float* __restrict__ Abuf, float* __restrict__ part,
                     const int tid, const float* __restrict__ W1) {
  const int q = tid >> 8;
  const int c0 = (tid & 255) << 1;
  const float* Wp = W1 + (size_t)(q * 128) * NH + c0;
  const float* Ar = Abuf + q * 128;
  float a0[PC], a1[PC];
#pragma unroll
  for (int r = 0; r < PC; ++r) { a0[r] = 0.f; a1[r] = 0.f; }
  float2 n0 = *(const float2*)Wp;
  float2 n1 = *(const float2*)(Wp + NH);
  float2 n2 = *(const float2*)(Wp + 2 * NH);
  float2 n3 = *(const float2*)(Wp + 3 * NH);
#pragma unroll 2
  for (int kc = 0; kc < 124; kc += 4) {
    const float2 w0 = n0, w1 = n1, w2 = n2, w3 = n3;
    const float* Wn = Wp + (size_t)(kc + 4) * NH;
    n0 = *(const float2*)Wn;
    n1 = *(const float2*)(Wn + NH);
    n2 = *(const float2*)(Wn + 2 * NH);
    n3 = *(const float2*)(Wn + 3 * NH);
#pragma unroll
    for (int r = 0; r < PC; ++r) {
      const float4 av = *(const float4*)(Ar + r * 512 + kc);
      a0[r] += av.x * w0.x + av.y * w1.x + av.z * w2.x + av.w * w3.x;
      a1[r] += av.x * w0.y + av.y * w1.y + av.z * w2.y + av.w * w3.y;
    }
  }
#pragma unroll
  for (int r = 0; r < PC; ++r) {
    const float4 av = *(const float4*)(Ar + r * 512 + 124);
    a0[r] += av.x * n0.x + av.y * n1.x + av.z * n2.x + av.w * n3.x;
    a1[r] += av.x * n0.y + av.y * n1.y + av.z * n2.y + av.w * n3.y;
  }
#pragma unroll
  for (int r = 0; r < PC; ++r)
    *(float2*)&part[(q * PC + r) * 512 + c0] = make_float2(a0[r], a1[r]);
}

template <int RT>
__device__ void g2ks(const float* __restrict__ hid, const int hidBase,
                     float* __restrict__ part, const int tid,
                     const float* __restrict__ W2) {
  const int q = tid >> 7;
  const int c0 = (tid & 127) << 1;
  const float* Wp = W2 + (size_t)(q * 64) * ND + c0;
  const float* Hr = hid + hidBase * 512 + q * 64;
  float a0[RT], a1[RT];
#pragma unroll
  for (int r = 0; r < RT; ++r) { a0[r] = 0.f; a1[r] = 0.f; }
  float2 n0 = *(const float2*)Wp;
  float2 n1 = *(const float2*)(Wp + ND);
  float2 n2 = *(const float2*)(Wp + 2 * ND);
  float2 n3 = *(const float2*)(Wp + 3 * ND);
#pragma unroll 2
  for (int kc = 0; kc < 60; kc += 4) {
    const float2 w0 = n0, w1 = n1, w2 = n2, w3 = n3;
    const float* Wn = Wp + (size_t)(kc + 4) * ND;
    n0 = *(const float2*)Wn;
    n1 = *(const float2*)(Wn + ND);
    n2 = *(const float2*)(Wn + 2 * ND);
    n3 = *(const float2*)(Wn + 3 * ND);
#pragma unroll
    for (int r = 0; r < RT; ++r) {
      const float4 av = *(const float4*)(Hr + r * 512 + kc);
      a0[r] += av.x * w0.x + av.y * w1.x + av.z * w2.x + av.w * w3.x;
      a1[r] += av.x * w0.y + av.y * w1.y + av.z * w2.y + av.w * w3.y;
    }
  }
#pragma unroll
  for (int r = 0; r < RT; ++r) {
    const float4 av = *(const float4*)(Hr + r * 512 + 60);
    a0[r] += av.x * n0.x + av.y * n1.x + av.z * n2.x + av.w * n3.x;
    a1[r] += av.x * n0.y + av.y * n1.y + av.z * n2.y + av.w * n3.y;
  }
#pragma unroll
  for (int r = 0; r < RT; ++r)
    *(float2*)&part[(q * RT + r) * 256 + c0] = make_float2(a0[r], a1[r]);
}

// ============== new col-quad engines (f4 weights, half the DS reads) ========
// g1q: 8 k-eighths (q=tid>>7) x 128 col-quads; zero weight redundancy.
template <int PC>
__device__ void g1q(const float* __restrict__ Abuf, float* __restrict__ part,
                    const int tid, const float* __restrict__ W1) {
  const int q = tid >> 7;
  const int c0 = (tid & 127) << 2;
  const float* Wp = W1 + (size_t)(q * 64) * NH + c0;
  const float* Ar = Abuf + q * 64;
  float a0[PC], a1[PC], a2[PC], a3[PC];
#pragma unroll
  for (int r = 0; r < PC; ++r) { a0[r] = 0.f; a1[r] = 0.f; a2[r] = 0.f; a3[r] = 0.f; }
  float4 n0 = *(const float4*)Wp;
  float4 n1 = *(const float4*)(Wp + NH);
  float4 n2 = *(const float4*)(Wp + 2 * NH);
  float4 n3 = *(const float4*)(Wp + 3 * NH);
#pragma unroll 2
  for (int kc = 0; kc < 60; kc += 4) {
    const float4 w0 = n0, w1 = n1, w2 = n2, w3 = n3;
    const float* Wn = Wp + (size_t)(kc + 4) * NH;
    n0 = *(const float4*)Wn;
    n1 = *(const float4*)(Wn + NH);
    n2 = *(const float4*)(Wn + 2 * NH);
    n3 = *(const float4*)(Wn + 3 * NH);
#pragma unroll
    for (int r = 0; r < PC; ++r) {
      const float4 av = *(const float4*)(Ar + r * 512 + kc);
      a0[r] += av.x * w0.x + av.y * w1.x + av.z * w2.x + av.w * w3.x;
      a1[r] += av.x * w0.y + av.y * w1.y + av.z * w2.y + av.w * w3.y;
      a2[r] += av.x * w0.z + av.y * w1.z + av.z * w2.z + av.w * w3.z;
      a3[r] += av.x * w0.w + av.y * w1.w + av.z * w2.w + av.w * w3.w;
    }
  }
#pragma unroll
  for (int r = 0; r < PC; ++r) {
    const float4 av = *(const float4*)(Ar + r * 512 + 60);
    a0[r] += av.x * n0.x + av.y * n1.x + av.z * n2.x + av.w * n3.x;
    a1[r] += av.x * n0.y + av.y * n1.y + av.z * n2.y + av.w * n3.y;
    a2[r] += av.x * n0.z + av.y * n1.z + av.z * n2.z + av.w * n3.z;
    a3[r] += av.x * n0.w + av.y * n1.w + av.z * n2.w + av.w * n3.w;
  }
#pragma unroll
  for (int r = 0; r < PC; ++r)
    *(float4*)&part[(q * PC + r) * 512 + c0] = make_float4(a0[r], a1[r], a2[r], a3[r]);
}

// g2q: 16 k-sixteenths (q=tid>>6) x 64 col-quads; zero redundancy. RT<=5.
template <int RT>
__device__ void g2q(const float* __restrict__ hid, const int hidBase,
                    float* __restrict__ part, const int tid,
                    const float* __restrict__ W2) {
  const int q = tid >> 6;
  const int c0 = (tid & 63) << 2;
  const float* Wp = W2 + (size_t)(q * 32) * ND + c0;
  const float* Hr = hid + hidBase * 512 + q * 32;
  float a0[RT], a1[RT], a2[RT], a3[RT];
#pragma unroll
  for (int r = 0; r < RT; ++r) { a0[r] = 0.f; a1[r] = 0.f; a2[r] = 0.f; a3[r] = 0.f; }
  float4 n0 = *(const float4*)Wp;
  float4 n1 = *(const float4*)(Wp + ND);
  float4 n2 = *(const float4*)(Wp + 2 * ND);
  float4 n3 = *(const float4*)(Wp + 3 * ND);
#pragma unroll 2
  for (int kc = 0; kc < 28; kc += 4) {
    const float4 w0 = n0, w1 = n1, w2 = n2, w3 = n3;
    const float* Wn = Wp + (size_t)(kc + 4) * ND;
    n0 = *(const float4*)Wn;
    n1 = *(const float4*)(Wn + ND);
    n2 = *(const float4*)(Wn + 2 * ND);
    n3 = *(const float4*)(Wn + 3 * ND);
#pragma unroll
    for (int r = 0; r < RT; ++r) {
      const float4 av = *(const float4*)(Hr + r * 512 + kc);
      a0[r] += av.x * w0.x + av.y * w1.x + av.z * w2.x + av.w * w3.x;
      a1[r] += av.x * w0.y + av.y * w1.y + av.z * w2.y + av.w * w3.y;
      a2[r] += av.x * w0.z + av.y * w1.z + av.z * w2.z + av.w * w3.z;
      a3[r] += av.x * w0.w + av.y * w1.w + av.z * w2.w + av.w * w3.w;
    }
  }
#pragma unroll
  for (int r = 0; r < RT; ++r) {
    const float4 av = *(const float4*)(Hr + r * 512 + 28);
    a0[r] += av.x * n0.x + av.y * n1.x + av.z * n2.x + av.w * n3.x;
    a1[r] += av.x * n0.y + av.y * n1.y + av.z * n2.y + av.w * n3.y;
    a2[r] += av.x * n0.z + av.y * n1.z + av.z * n2.z + av.w * n3.z;
    a3[r] += av.x * n0.w + av.y * n1.w + av.z * n2.w + av.w * n3.w;
  }
#pragma unroll
  for (int r = 0; r < RT; ++r)
    *(float4*)&part[(q * RT + r) * 256 + c0] = make_float4(a0[r], a1[r], a2[r], a3[r]);
}

// ================= reduce phases (KS-templated) ==============================
template <int KS, int PC>
__device__ void g1red(const float* __restrict__ part, float* __restrict__ hid,
                      const int tid, const float* __restrict__ b1,
                      const int isBn, const float* __restrict__ embS,
                      const int* __restrict__ bitR) {
  for (int i = tid; i < PC * 256; i += NT) {
    const int r = i >> 8, c0 = (i & 255) << 1;
    float2 s = *(const float2*)(b1 + c0);
#pragma unroll
    for (int qq = 0; qq < KS; ++qq) {
      const float2 p = *(const float2*)&part[(qq * PC + r) * 512 + c0];
      s.x += p.x; s.y += p.y;
    }
    if (isBn) {
      const float2 e = *(const float2*)&embS[bitR[r] * 512 + c0];
      s.x += e.x; s.y += e.y;
    }
    *(float2*)&hid[r * 512 + c0] = make_float2(fmaxf(s.x, 0.f), fmaxf(s.y, 0.f));
  }
}

template <int KS, int R>
__device__ void g1redspec(const float* __restrict__ part, float* __restrict__ hid,
                          const int base, const int tid,
                          const float* __restrict__ b1,
                          const float* __restrict__ embS) {
  for (int i = tid; i < R * 256; i += NT) {
    const int r = i >> 8, c0 = (i & 255) << 1;
    float2 s = *(const float2*)(b1 + c0);
#pragma unroll
    for (int qq = 0; qq < KS; ++qq) {
      const float2 p = *(const float2*)&part[(qq * R + r) * 512 + c0];
      s.x += p.x; s.y += p.y;
    }
    const float2 e0 = *(const float2*)&embS[c0];
    const float2 e1 = *(const float2*)&embS[512 + c0];
    *(float2*)&hid[(base + 2 * r) * 512 + c0] =
        make_float2(fmaxf(s.x + e0.x, 0.f), fmaxf(s.y + e0.y, 0.f));
    *(float2*)&hid[(base + 2 * r + 1) * 512 + c0] =
        make_float2(fmaxf(s.x + e1.x, 0.f), fmaxf(s.y + e1.y, 0.f));
  }
}

template <int KS, int RT>
__device__ void g2red(const float* __restrict__ part, const int tid,
                      const float* __restrict__ b2,
                      float* const* __restrict__ rowDst) {
  for (int i = tid; i < RT * 128; i += NT) {
    const int r = i >> 7, c0 = (i & 127) << 1;
    float2 s = *(const float2*)(b2 + c0);
#pragma unroll
    for (int qq = 0; qq < KS; ++qq) {
      const float2 p = *(const float2*)&part[(qq * RT + r) * 256 + c0];
      s.x += p.x; s.y += p.y;
    }
    *(float2*)(rowDst[r] + c0) = s;
  }
}

__global__ __launch_bounds__(NT, 4) void sc_quad(
    const int* __restrict__ info_bits, const float* __restrict__ rv,
    const int* __restrict__ info_set,
    const float* __restrict__ obs_emb, const float* __restrict__ label_emb,
    const float* __restrict__ cnW1, const float* __restrict__ cnb1,
    const float* __restrict__ cnW2, const float* __restrict__ cnb2,
    const float* __restrict__ bnW1, const float* __restrict__ bnb1,
    const float* __restrict__ bnW2, const float* __restrict__ bnb2,
    const float* __restrict__ llrW, const float* __restrict__ llrb,
    float* __restrict__ out, float* __restrict__ ws) {
  __shared__ float A[4096];       // <=8 staged input rows
  __shared__ float part[20480];   // k-split partials
  __shared__ float hid[8192];     // <=16 hidden rows
  __shared__ float embS[1024];    // label_emb[bit] @ bnW1[512:768]
  __shared__ float rowBuf[256];   // uniform-pass single output row
  __shared__ float* rowDst[16];
  __shared__ int fmap[256];
  __shared__ int curS[256], nxtS[256];
  __shared__ float red[8];
  __shared__ int bitR[8];
  __shared__ int qbS[4];

  const int tid = threadIdx.x, b = blockIdx.x;
  float* wsb = ws + (size_t)b * BPB;
  float* E = wsb;
  float* sp6 = wsb + SP6O;
  float* S1 = wsb + S1O;
  float* S2 = wsb + S2O;
  float* S3 = wsb + S3O;
  int* Lb = (int*)(wsb + LOFFI);
  const float* obs2 = obs_emb + 2 * ND;

  // ---- init: embC + fmap ----
  {
    const int bit = tid >> 9, col = tid & 511;
    float s = 0.f;
#pragma unroll 4
    for (int j = 0; j < ND; ++j)
      s += label_emb[bit * ND + j] * bnW1[(size_t)(NH + j) * NH + col];
    embS[bit * 512 + col] = s;
  }
  if (tid < 256) fmap[tid] = -1;
  __syncthreads();
  if (tid < NK) fmap[info_set[tid]] = tid;
  __syncthreads();

  auto stageA = [&](const float* Ed, int p0, int R) {
    const int n4 = R * 128;
    float4* A4 = (float4*)A;
    if (Ed) {
      const float4* s4 = (const float4*)(Ed + (size_t)(2 * p0) * ND);
      for (int i = tid; i < n4; i += NT) A4[i] = s4[i];
    } else {
      const float4* o4 = (const float4*)obs2;
      for (int i = tid; i < n4; i += NT) A4[i] = o4[i & 63];
    }
  };

  auto plainPass = [&](int d, int isBn) {
    const int P = 1 << (7 - d);
    const float* W1 = isBn ? bnW1 : cnW1;
    const float* B1 = isBn ? bnb1 : cnb1;
    const float* W2 = isBn ? bnW2 : cnW2;
    const float* B2 = isBn ? bnb2 : cnb2;
    const float* Ed = (d == 0) ? nullptr : E + (size_t)loff(d) * ND;
    float* dstE = E + (size_t)loff(d + 1) * ND;
    const int PC = P >= 8 ? 8 : 4;
    for (int p0 = 0; p0 < P; p0 += PC) {
      stageA(Ed, p0, PC);
      if (isBn && tid < PC) bitR[tid] = Lb[loff(d + 1) + p0 + tid];
      if (tid < PC) rowDst[tid] = dstE + (size_t)(p0 + tid) * ND;
      __syncthreads();
      if (PC == 8) {
        g1ks<8>(A, part, tid, W1); __syncthreads();
        g1red<4, 8>(part, hid, tid, B1, isBn, embS, bitR); __syncthreads();
        g2ks<8>(hid, 0, part, tid, W2); __syncthreads();
        g2red<8, 8>(part, tid, B2, rowDst); __syncthreads();
      } else {
        g1q<4>(A, part, tid, W1); __syncthreads();
        g1red<8, 4>(part, hid, tid, B1, isBn, embS, bitR); __syncthreads();
        g2q<4>(hid, 0, part, tid, W2); __syncthreads();
        g2red<16, 4>(part, tid, B2, rowDst); __syncthreads();
      }
    }
  };

  // uniform initial-descent pass (verified R10/R11): 1 row + broadcast store
  auto uniPass = [&](int d) {
    const int P = 1 << (7 - d);
    const float* Ed = (d == 0) ? nullptr : E + (size_t)loff(d) * ND;
    float* dstE = E + (size_t)loff(d + 1) * ND;
    stageA(Ed, 0, 1);
    if (tid == 0) rowDst[0] = rowBuf;
    __syncthreads();
    g1q<1>(A, part, tid, cnW1); __syncthreads();
    g1red<8, 1>(part, hid, tid, cnb1, 0, embS, bitR); __syncthreads();
    g2q<1>(hid, 0, part, tid, cnW2); __syncthreads();
    g2red<16, 1>(part, tid, cnb2, rowDst); __syncthreads();
    for (int i = tid; i < P * 256; i += NT) dstE[i] = rowBuf[i & 255];
    __syncthreads();
  };

  // depth-6 pair: cn6 (2 rows -> E7) + bn6 spec (2 rows x 2 bits -> sp6[0..3])
  auto pair6 = [&]() {
    stageA(E + (size_t)loff(6) * ND, 0, 2);
    if (tid < 2) rowDst[tid] = E + (size_t)(252 + tid) * ND;
    __syncthreads();
    g1q<2>(A, part, tid, cnW1); __syncthreads();
    g1red<8, 2>(part, hid, tid, cnb1, 0, embS, bitR); __syncthreads();
    g2q<2>(hid, 0, part, tid, cnW2); __syncthreads();
    g2red<16, 2>(part, tid, cnb2, rowDst); __syncthreads();
    g1q<2>(A, part, tid, bnW1); __syncthreads();
    g1redspec<8, 2>(part, hid, 2, tid, bnb1, embS); __syncthreads();
    g2q<4>(hid, 2, part, tid, bnW2);
    if (tid < 4) rowDst[tid] = sp6 + (size_t)tid * ND;
    __syncthreads();
    g2red<16, 4>(part, tid, bnb2, rowDst); __syncthreads();
  };

  // depth-7 combined: 5 A rows -> cn {E8, S2[0..3]} + bn-spec {S1[0..1], S3[0..7]}
  auto comb = [&]() {
    for (int i = tid; i < 5 * 128; i += NT) {
      const int r = i >> 7, k = (i & 127) << 2;
      const int h = k >> 8;
      const float* src;
      if (r == 0) src = E + (size_t)(252 + h) * ND;
      else {
        const int cc = r - 1;
        const int bit = (h == 0) ? (cc >> 1) : (cc & 1);
        src = sp6 + (size_t)(h * 2 + bit) * ND;
      }
      *(float4*)&A[r * 512 + k] = *(const float4*)&src[k & 255];
    }
    __syncthreads();
    g1q<5>(A, part, tid, cnW1); __syncthreads();
    g1red<8, 5>(part, hid, tid, cnb1, 0, embS, bitR); __syncthreads();
    g2q<5>(hid, 0, part, tid, cnW2);
    if (tid < 5) rowDst[tid] = (tid == 0) ? (E + (size_t)254 * ND)
                                          : (S2 + (size_t)(tid - 1) * ND);
    __syncthreads();
    g2red<16, 5>(part, tid, cnb2, rowDst); __syncthreads();
    g1q<5>(A, part, tid, bnW1); __syncthreads();
    g1redspec<8, 5>(part, hid, 5, tid, bnb1, embS); __syncthreads();
    g2ks<10>(hid, 5, part, tid, bnW2);
    if (tid < 10) rowDst[tid] = (tid < 2) ? (S1 + (size_t)tid * ND)
                                          : (S3 + (size_t)(tid - 2) * ND);
    __syncthreads();
    g2red<8, 10>(part, tid, bnb2, rowDst); __syncthreads();
  };

  auto leaf = [&](int off) {
    const int ph = off & 3;
    const float* src;
    if (ph == 0) src = E + (size_t)254 * ND;
    else if (ph == 1) src = S1 + (size_t)qbS[0] * ND;
    else {
      const int cidx = 2 * (qbS[0] ^ qbS[1]) + qbS[1];
      src = (ph == 2) ? (S2 + (size_t)cidx * ND)
                      : (S3 + (size_t)(2 * cidx + qbS[2]) * ND);
    }
    if (tid < 256) {
      const float ev = src[tid];
      float v0 = ev * llrW[2 * tid];
      float v1 = ev * llrW[2 * tid + 1];
#pragma unroll
      for (int o = 32; o > 0; o >>= 1) {
        v0 += __shfl_down(v0, o);
        v1 += __shfl_down(v1, o);
      }
      if ((tid & 63) == 0) {
        red[tid >> 6] = v0;
        red[4 + (tid >> 6)] = v1;
      }
    }
    __syncthreads();
    if (tid == 0) {
      const float l0 = red[0] + red[1] + red[2] + red[3] + llrb[0];
      const float l1 = red[4] + red[5] + red[6] + red[7] + llrb[1];
      const float m = fmaxf(l0, l1);
      const float e0 = expf(l0 - m), e1 = expf(l1 - m);
      const float s = e0 + e1;
      const float p0 = e0 / s, p1 = e1 / s;
      const int hard = (rv[b * NN + off] > p0) ? 1 : 0;
      const int fidx = fmap[off];
      const int fval = (fidx >= 0) ? info_bits[b * NK + fidx] : 2;
      const int xb = (fval == 2) ? hard : fval;
      out[OUT_F + b * NN + off] = (fidx >= 0) ? 2.0f : (float)xb;
      out[OUT_U + b * NN + off] = (float)xb;
      out[OUT_P + (b * NN + off) * 2 + 0] = p0;
      out[OUT_P + (b * NN + off) * 2 + 1] = p1;
      curS[0] = xb;
      qbS[ph] = xb;
    }
    __syncthreads();
    int* cur = curS;
    int* nxt = nxtS;
    int len = 1, lev = 8, idx = off;
    while (idx & 1) {
      if (tid < len) {
        const int c = cur[tid];
        nxt[2 * tid] = Lb[loff(lev) + tid] ^ c;
        nxt[2 * tid + 1] = c;
      }
      __syncthreads();
      int* t = cur; cur = nxt; nxt = t;
      len <<= 1; idx >>= 1; --lev;
    }
    if (lev > 0) {
      if (tid < len) Lb[loff(lev) + tid] = cur[tid];
    } else {
      if (tid < 256) out[OUT_X + b * NN + tid] = (float)cur[tid];
    }
    __syncthreads();
  };

  // ---- initial descent (uniform rows -> 1-row passes) ----
  for (int d = 0; d <= 5; ++d) uniPass(d);
  pair6();
  comb();

  // ---- leaf loop ----
  for (int off = 0; off < NN; ++off) {
    leaf(off);
    if (off == NN - 1) break;
    const int t = off + 1;
    const int z = __ffs(t) - 1;
    if (z <= 1) continue;  // inside a quad: everything pre-speculated
    const int dbn = 7 - z;  // <= 5
    plainPass(dbn, 1);
    for (int d = dbn + 1; d <= 5; ++d) plainPass(d, 0);
    pair6();
    comb();
  }
}

extern "C" void kernel_launch(void* const* d_in, const int* in_sizes, int n_in,
                              void* d_out, int out_size, void* d_ws, size_t ws_size,
                              hipStream_t stream) {
  const int*   info_bits = (const int*)d_in[0];
  const float* rv        = (const float*)d_in[1];
  const int*   info_set  = (const int*)d_in[2];
  const float* obs_emb   = (const float*)d_in[3];
  const float* label_emb = (const float*)d_in[4];
  const float* cnW1      = (const float*)d_in[5];
  const float* cnb1      = (const float*)d_in[6];
  const float* cnW2      = (const float*)d_in[7];
  const float* cnb2      = (const float*)d_in[8];
  const float* bnW1      = (const float*)d_in[9];
  const float* bnb1      = (const float*)d_in[10];
  const float* bnW2      = (const float*)d_in[11];
  const float* bnb2      = (const float*)d_in[12];
  const float* llrW      = (const float*)d_in[13];
  const float* llrb      = (const float*)d_in[14];

  float* out = (float*)d_out;
  float* ws  = (float*)d_ws;

  sc_quad<<<dim3(NB), dim3(NT), 0, stream>>>(
      info_bits, rv, info_set, obs_emb, label_emb,
      cnW1, cnb1, cnW2, cnb2, bnW1, bnb1, bnW2, bnb2,
      llrW, llrb, out, ws);
}